// Round 2
// baseline (701.431 us; speedup 1.0000x reference)
//
#include <hip/hip_runtime.h>

typedef _Float16 f16x8 __attribute__((ext_vector_type(8)));
typedef _Float16 f16x4 __attribute__((ext_vector_type(4)));
typedef float    f32x4 __attribute__((ext_vector_type(4)));

#define BN    128          // points per block
#define KPAD  288          // padded K width for the skip layer
#define ROWB  (KPAD * 2)   // 576 bytes per LDS row
#define WELE  270336       // fp16 elements per weight bank (hi or lo)

// XOR swizzle on the 16B-slot index for cols 0..255 (bytes 0..511).
// Bytes 512..575 (the x/zero pad cols) stay linear so the swizzle never
// escapes the row.
__device__ __forceinline__ int swz(int row, int colb) {
  int c = (colb < 512) ? (colb ^ ((row & 7) << 4)) : colb;
  return row * ROWB + c;
}

__device__ __forceinline__ float gabor_f(float lin) {
  float a = 10.f * lin;                 // OMEGA == SIGMA == 10
  return __cosf(a) * __expf(-a * a);
}

// One 256-out gabor layer with split-precision weights:
// out[p][n] = gabor( sum_k in[p][k]*(Whi+Wlo)[n][k] + bias[n] )
// A-operand = W tile (16 units x 32 k), B-operand = H tile (32 k x 16 points).
// D: row = unit = (lane>>4)*4+reg, col = point = lane&15.
template <int KSTEPS>
__device__ __forceinline__ void mfma_layer(const char* __restrict__ inb,
                                           char* __restrict__ outb,
                                           const _Float16* __restrict__ Whi,
                                           const _Float16* __restrict__ Wlo,
                                           const float* __restrict__ bias,
                                           int lane, int n0, int p0) {
  const int r = lane & 15;
  const int g = lane >> 4;
  f32x4 acc[4][4];
#pragma unroll
  for (int i = 0; i < 4; i++)
#pragma unroll
    for (int j = 0; j < 4; j++) {
      f32x4 z = {0.f, 0.f, 0.f, 0.f};
      acc[i][j] = z;
    }

#pragma unroll
  for (int kk = 0; kk < KSTEPS; kk++) {
    const int kb = kk * 32 + g * 8;     // k element offset for this lane group
    f16x8 a[4], c[4], b[4];
#pragma unroll
    for (int i = 0; i < 4; i++) {
      const size_t off = (size_t)(n0 + i * 16 + r) * (KSTEPS * 32) + kb;
      a[i] = *(const f16x8*)(Whi + off);
      c[i] = *(const f16x8*)(Wlo + off);
    }
#pragma unroll
    for (int j = 0; j < 4; j++)
      b[j] = *(const f16x8*)(inb + swz(p0 + j * 16 + r, kb * 2));
#pragma unroll
    for (int i = 0; i < 4; i++)
#pragma unroll
      for (int j = 0; j < 4; j++)
        acc[i][j] = __builtin_amdgcn_mfma_f32_16x16x32_f16(a[i], b[j], acc[i][j], 0, 0, 0);
#pragma unroll
    for (int i = 0; i < 4; i++)
#pragma unroll
      for (int j = 0; j < 4; j++)
        acc[i][j] = __builtin_amdgcn_mfma_f32_16x16x32_f16(c[i], b[j], acc[i][j], 0, 0, 0);
  }

  // epilogue: +bias, gabor, pack 4 consecutive units -> one ds_write_b64
#pragma unroll
  for (int i = 0; i < 4; i++) {
    const f32x4 bv = *(const f32x4*)(bias + n0 + i * 16 + g * 4);
#pragma unroll
    for (int j = 0; j < 4; j++) {
      f16x4 hv;
#pragma unroll
      for (int e = 0; e < 4; e++)
        hv[e] = (_Float16)gabor_f(acc[i][j][e] + bv[e]);
      *(f16x4*)(outb + swz(p0 + j * 16 + r, (n0 + i * 16 + g * 4) * 2)) = hv;
    }
  }
}

extern "C" __global__ void __launch_bounds__(512, 1)
inr_fused(const float* __restrict__ x, const float* __restrict__ W0,
          const float* __restrict__ b0, const float* __restrict__ b1,
          const float* __restrict__ b2, const float* __restrict__ b3,
          const float* __restrict__ b4, const float* __restrict__ Wf,
          const float* __restrict__ bf, const _Float16* __restrict__ wsh,
          float* __restrict__ out, int npts) {
  extern __shared__ char smem[];
  char* bufA = smem;
  char* bufB = smem + BN * ROWB;

  const _Float16* w1h = wsh;
  const _Float16* w2h = wsh + 65536;
  const _Float16* w4h = wsh + 131072;
  const _Float16* w3p = wsh + 196608;   // [256][288], zero-padded
  const _Float16* w1l = wsh + WELE;
  const _Float16* w2l = wsh + WELE + 65536;
  const _Float16* w4l = wsh + WELE + 131072;
  const _Float16* w3l = wsh + WELE + 196608;

  const int tid   = threadIdx.x;
  const int pbase = blockIdx.x * BN;

  // ---- layer 0: K=3 linear + gabor, fp32 VALU; also fill skip cols ----
  {
    const int p = tid >> 2;             // 128 points, 4 threads each
    const int q = tid & 3;              // each thread: 64 units
    const int gp = pbase + p;
    float x0 = 0.f, x1 = 0.f, x2 = 0.f;
    if (gp < npts) {
      x0 = x[(size_t)gp * 3 + 0];
      x1 = x[(size_t)gp * 3 + 1];
      x2 = x[(size_t)gp * 3 + 2];
    }
#pragma unroll
    for (int ub = 0; ub < 64; ub += 8) {
      const int u0 = q * 64 + ub;
      f16x8 hv;
#pragma unroll
      for (int e = 0; e < 8; e++) {
        const int u = u0 + e;
        float lin = fmaf(x0, W0[u * 3 + 0],
                    fmaf(x1, W0[u * 3 + 1],
                    fmaf(x2, W0[u * 3 + 2], b0[u])));
        hv[e] = (_Float16)gabor_f(lin);
      }
      *(f16x8*)(bufA + swz(p, u0 * 2)) = hv;
    }
    // skip-concat cols 256..287 of bufA: [x0,x1,x2, 0...0]
    f16x8 xv = {(_Float16)0.f, (_Float16)0.f, (_Float16)0.f, (_Float16)0.f,
                (_Float16)0.f, (_Float16)0.f, (_Float16)0.f, (_Float16)0.f};
    if (q == 0) { xv[0] = (_Float16)x0; xv[1] = (_Float16)x1; xv[2] = (_Float16)x2; }
    *(f16x8*)(bufA + swz(p, (256 + q * 8) * 2)) = xv;
  }
  __syncthreads();

  const int lane = tid & 63;
  const int wid  = tid >> 6;            // 8 waves: 4 unit-slices x 2 point-slices
  const int n0   = (wid & 3) * 64;
  const int p0   = (wid >> 2) * 64;

  mfma_layer<8>(bufA, bufB, w1h, w1l, b1, lane, n0, p0);   // L1: A -> B
  __syncthreads();
  mfma_layer<8>(bufB, bufA, w2h, w2l, b2, lane, n0, p0);   // L2: B -> A (keeps skip cols)
  __syncthreads();
  mfma_layer<9>(bufA, bufB, w3p, w3l, b3, lane, n0, p0);   // L3: K=288 (skip folded in)
  __syncthreads();
  mfma_layer<8>(bufB, bufA, w4h, w4l, b4, lane, n0, p0);   // L4: B -> A
  __syncthreads();

  // ---- final linear: 3 outputs per point, fp32 VALU ----
  if (tid < BN * 3) {
    const int p = tid / 3;
    const int o = tid - p * 3;
    const int gp = pbase + p;
    if (gp < npts) {
      float acc = bf[o];
#pragma unroll 4
      for (int k = 0; k < 256; k += 8) {
        f16x8 hv = *(const f16x8*)(bufA + swz(p, k * 2));
        f32x4 wa = *(const f32x4*)(Wf + o * 256 + k);
        f32x4 wb = *(const f32x4*)(Wf + o * 256 + k + 4);
        acc = fmaf((float)hv[0], wa[0], acc);
        acc = fmaf((float)hv[1], wa[1], acc);
        acc = fmaf((float)hv[2], wa[2], acc);
        acc = fmaf((float)hv[3], wa[3], acc);
        acc = fmaf((float)hv[4], wb[0], acc);
        acc = fmaf((float)hv[5], wb[1], acc);
        acc = fmaf((float)hv[6], wb[2], acc);
        acc = fmaf((float)hv[7], wb[3], acc);
      }
      out[(size_t)gp * 3 + o] = acc;
    }
  }
}

// fp32 -> split fp16 (hi + lo residual) weight conversion into workspace:
// whi bank at [0, WELE), wlo bank at [WELE, 2*WELE). Within each bank:
// [0,65536)    W1 [256][256]
// [65536,..)   W2 [256][256]
// [131072,..)  W4 [256][256]
// [196608,..)  W3 [256][288] zero-padded from [256][259]
extern "C" __global__ void conv_w(const float* __restrict__ W1,
                                  const float* __restrict__ W2,
                                  const float* __restrict__ W4,
                                  const float* __restrict__ W3,
                                  _Float16* __restrict__ wsh) {
  int idx = blockIdx.x * blockDim.x + threadIdx.x;
  float w = 0.f;
  bool valid = false;
  if (idx < 196608) {
    int which = idx >> 16, k = idx & 65535;
    const float* s = (which == 0) ? W1 : ((which == 1) ? W2 : W4);
    w = s[k];
    valid = true;
  } else if (idx < WELE) {
    int t = idx - 196608;
    int j = t / 288, k = t - j * 288;
    w = (k < 259) ? W3[(size_t)j * 259 + k] : 0.f;
    valid = true;
  }
  if (valid) {
    _Float16 hi = (_Float16)w;
    _Float16 lo = (_Float16)(w - (float)hi);
    wsh[idx] = hi;
    wsh[idx + WELE] = lo;
  }
}

extern "C" void kernel_launch(void* const* d_in, const int* in_sizes, int n_in,
                              void* d_out, int out_size, void* d_ws, size_t ws_size,
                              hipStream_t stream) {
  const float* x  = (const float*)d_in[0];
  const float* W0 = (const float*)d_in[1];
  const float* b0 = (const float*)d_in[2];
  const float* W1 = (const float*)d_in[3];
  const float* b1 = (const float*)d_in[4];
  const float* W2 = (const float*)d_in[5];
  const float* b2 = (const float*)d_in[6];
  const float* W3 = (const float*)d_in[7];
  const float* b3 = (const float*)d_in[8];
  const float* W4 = (const float*)d_in[9];
  const float* b4 = (const float*)d_in[10];
  const float* Wf = (const float*)d_in[11];
  const float* bf = (const float*)d_in[12];
  float* out      = (float*)d_out;
  _Float16* wsh   = (_Float16*)d_ws;    // needs 2*WELE*2 B = 1081344 B

  const int npts = in_sizes[0] / 3;

  conv_w<<<(WELE + 511) / 512, 512, 0, stream>>>(W1, W2, W4, W3, wsh);

  const int nblk = (npts + BN - 1) / BN;
  inr_fused<<<nblk, 512, 2 * BN * ROWB, stream>>>(x, W0, b0, b1, b2, b3, b4,
                                                  Wf, bf, wsh, out, npts);
}

// Round 5
// 628.167 us; speedup vs baseline: 1.1166x; 1.1166x over previous
//
#include <hip/hip_runtime.h>

typedef _Float16 f16x8 __attribute__((ext_vector_type(8)));
typedef _Float16 f16x4 __attribute__((ext_vector_type(4)));
typedef float    f32x4 __attribute__((ext_vector_type(4)));

#define BN    64           // points per block
#define KPAD  288          // padded K width for the skip layer
#define ROWB  (KPAD * 2)   // 576 bytes per LDS row
#define WELE  270336       // fp16 elements per weight bank (hi or lo)

// XOR swizzle on the 16B-slot index for cols 0..255 (bytes 0..511).
// Bytes 512..575 (the x/zero pad cols) stay linear so the swizzle never
// escapes the row.
__device__ __forceinline__ int swz(int row, int colb) {
  int c = (colb < 512) ? (colb ^ ((row & 7) << 4)) : colb;
  return row * ROWB + c;
}

__device__ __forceinline__ float gabor_f(float lin) {
  float a = 10.f * lin;                 // OMEGA == SIGMA == 10
  return __cosf(a) * __expf(-a * a);
}

// One 256-out gabor layer with split-precision weights.
// Wave wid owns units [n0, n0+32) for ALL 64 points (8 waves cover 256 units;
// W is streamed from L2 exactly once per block).
// A-operand = W tile (16 units x 32 k), B-operand = H tile (32 k x 16 points).
// D: row = unit = (lane>>4)*4+reg, col = point = lane&15.
template <int KSTEPS>
__device__ __forceinline__ void mfma_layer(const char* __restrict__ inb,
                                           char* __restrict__ outb,
                                           const _Float16* __restrict__ Whi,
                                           const _Float16* __restrict__ Wlo,
                                           const float* __restrict__ bias,
                                           int lane, int n0) {
  const int r = lane & 15;
  const int g = lane >> 4;
  f32x4 acc[2][4];
#pragma unroll
  for (int i = 0; i < 2; i++)
#pragma unroll
    for (int j = 0; j < 4; j++) {
      f32x4 z = {0.f, 0.f, 0.f, 0.f};
      acc[i][j] = z;
    }

#pragma unroll
  for (int kk = 0; kk < KSTEPS; kk++) {
    const int kb = kk * 32 + g * 8;     // k element offset for this lane group
    f16x8 a[2], c[2], b[4];
#pragma unroll
    for (int i = 0; i < 2; i++) {
      const size_t off = (size_t)(n0 + i * 16 + r) * (KSTEPS * 32) + kb;
      a[i] = *(const f16x8*)(Whi + off);
      c[i] = *(const f16x8*)(Wlo + off);
    }
#pragma unroll
    for (int j = 0; j < 4; j++)
      b[j] = *(const f16x8*)(inb + swz(j * 16 + r, kb * 2));
#pragma unroll
    for (int i = 0; i < 2; i++)
#pragma unroll
      for (int j = 0; j < 4; j++)
        acc[i][j] = __builtin_amdgcn_mfma_f32_16x16x32_f16(a[i], b[j], acc[i][j], 0, 0, 0);
#pragma unroll
    for (int i = 0; i < 2; i++)
#pragma unroll
      for (int j = 0; j < 4; j++)
        acc[i][j] = __builtin_amdgcn_mfma_f32_16x16x32_f16(c[i], b[j], acc[i][j], 0, 0, 0);
  }

  // epilogue: +bias, gabor, pack 4 consecutive units -> one ds_write_b64
#pragma unroll
  for (int i = 0; i < 2; i++) {
    const f32x4 bv = *(const f32x4*)(bias + n0 + i * 16 + g * 4);
#pragma unroll
    for (int j = 0; j < 4; j++) {
      f16x4 hv;
#pragma unroll
      for (int e = 0; e < 4; e++)
        hv[e] = (_Float16)gabor_f(acc[i][j][e] + bv[e]);
      *(f16x4*)(outb + swz(j * 16 + r, (n0 + i * 16 + g * 4) * 2)) = hv;
    }
  }
}

extern "C" __global__ void __launch_bounds__(512, 4)
inr_fused(const float* __restrict__ x, const float* __restrict__ W0,
          const float* __restrict__ b0, const float* __restrict__ b1,
          const float* __restrict__ b2, const float* __restrict__ b3,
          const float* __restrict__ b4, const float* __restrict__ Wf,
          const float* __restrict__ bf, const _Float16* __restrict__ wsh,
          float* __restrict__ out, int npts) {
  extern __shared__ char smem[];
  char* bufA = smem;
  char* bufB = smem + BN * ROWB;

  const _Float16* w1h = wsh;
  const _Float16* w2h = wsh + 65536;
  const _Float16* w4h = wsh + 131072;
  const _Float16* w3p = wsh + 196608;   // [256][288], zero-padded
  const _Float16* w1l = wsh + WELE;
  const _Float16* w2l = wsh + WELE + 65536;
  const _Float16* w4l = wsh + WELE + 131072;
  const _Float16* w3l = wsh + WELE + 196608;

  const int tid   = threadIdx.x;
  const int pbase = blockIdx.x * BN;

  // ---- layer 0: K=3 linear + gabor, fp32 VALU; also fill skip cols ----
  {
    const int p = tid >> 3;             // 64 points, 8 threads each
    const int q = tid & 7;              // each thread: 32 units
    const int gp = pbase + p;
    float x0 = 0.f, x1 = 0.f, x2 = 0.f;
    if (gp < npts) {
      x0 = x[(size_t)gp * 3 + 0];
      x1 = x[(size_t)gp * 3 + 1];
      x2 = x[(size_t)gp * 3 + 2];
    }
#pragma unroll
    for (int ub = 0; ub < 32; ub += 8) {
      const int u0 = q * 32 + ub;
      f16x8 hv;
#pragma unroll
      for (int e = 0; e < 8; e++) {
        const int u = u0 + e;
        float lin = fmaf(x0, W0[u * 3 + 0],
                    fmaf(x1, W0[u * 3 + 1],
                    fmaf(x2, W0[u * 3 + 2], b0[u])));
        hv[e] = (_Float16)gabor_f(lin);
      }
      *(f16x8*)(bufA + swz(p, u0 * 2)) = hv;
    }
    // skip-concat cols 256..287 of bufA: [x0,x1,x2, 0...0]
    if (q < 4) {
      f16x8 xv = {(_Float16)0.f, (_Float16)0.f, (_Float16)0.f, (_Float16)0.f,
                  (_Float16)0.f, (_Float16)0.f, (_Float16)0.f, (_Float16)0.f};
      if (q == 0) { xv[0] = (_Float16)x0; xv[1] = (_Float16)x1; xv[2] = (_Float16)x2; }
      *(f16x8*)(bufA + swz(p, (256 + q * 8) * 2)) = xv;
    }
  }
  __syncthreads();

  const int lane = tid & 63;
  const int wid  = tid >> 6;            // 8 waves: 8 unit-slices, all points
  const int n0   = wid * 32;

  mfma_layer<8>(bufA, bufB, w1h, w1l, b1, lane, n0);   // L1: A -> B
  __syncthreads();
  mfma_layer<8>(bufB, bufA, w2h, w2l, b2, lane, n0);   // L2: B -> A (keeps skip cols)
  __syncthreads();
  mfma_layer<9>(bufA, bufB, w3p, w3l, b3, lane, n0);   // L3: K=288 (skip folded in)
  __syncthreads();
  mfma_layer<8>(bufB, bufA, w4h, w4l, b4, lane, n0);   // L4: B -> A
  __syncthreads();

  // ---- final linear: 3 outputs per point, fp32 VALU ----
  if (tid < BN * 3) {
    const int p = tid / 3;
    const int o = tid - p * 3;
    const int gp = pbase + p;
    if (gp < npts) {
      float a0 = bf[o], a1 = 0.f, a2 = 0.f, a3 = 0.f;
#pragma unroll 4
      for (int k = 0; k < 256; k += 8) {
        f16x8 hv = *(const f16x8*)(bufA + swz(p, k * 2));
        f32x4 wa = *(const f32x4*)(Wf + o * 256 + k);
        f32x4 wb = *(const f32x4*)(Wf + o * 256 + k + 4);
        a0 = fmaf((float)hv[0], wa[0], a0);
        a1 = fmaf((float)hv[1], wa[1], a1);
        a2 = fmaf((float)hv[2], wa[2], a2);
        a3 = fmaf((float)hv[3], wa[3], a3);
        a0 = fmaf((float)hv[4], wb[0], a0);
        a1 = fmaf((float)hv[5], wb[1], a1);
        a2 = fmaf((float)hv[6], wb[2], a2);
        a3 = fmaf((float)hv[7], wb[3], a3);
      }
      out[(size_t)gp * 3 + o] = (a0 + a1) + (a2 + a3);
    }
  }
}

// fp32 -> split fp16 (hi + lo residual) weight conversion into workspace:
// whi bank at [0, WELE), wlo bank at [WELE, 2*WELE). Within each bank:
// [0,65536)    W1 [256][256]
// [65536,..)   W2 [256][256]
// [131072,..)  W4 [256][256]
// [196608,..)  W3 [256][288] zero-padded from [256][259]
extern "C" __global__ void conv_w(const float* __restrict__ W1,
                                  const float* __restrict__ W2,
                                  const float* __restrict__ W4,
                                  const float* __restrict__ W3,
                                  _Float16* __restrict__ wsh) {
  int idx = blockIdx.x * blockDim.x + threadIdx.x;
  float w = 0.f;
  bool valid = false;
  if (idx < 196608) {
    int which = idx >> 16, k = idx & 65535;
    const float* s = (which == 0) ? W1 : ((which == 1) ? W2 : W4);
    w = s[k];
    valid = true;
  } else if (idx < WELE) {
    int t = idx - 196608;
    int j = t / 288, k = t - j * 288;
    w = (k < 259) ? W3[(size_t)j * 259 + k] : 0.f;
    valid = true;
  }
  if (valid) {
    _Float16 hi = (_Float16)w;
    _Float16 lo = (_Float16)(w - (float)hi);
    wsh[idx] = hi;
    wsh[idx + WELE] = lo;
  }
}

extern "C" void kernel_launch(void* const* d_in, const int* in_sizes, int n_in,
                              void* d_out, int out_size, void* d_ws, size_t ws_size,
                              hipStream_t stream) {
  const float* x  = (const float*)d_in[0];
  const float* W0 = (const float*)d_in[1];
  const float* b0 = (const float*)d_in[2];
  const float* W1 = (const float*)d_in[3];
  const float* b1 = (const float*)d_in[4];
  const float* W2 = (const float*)d_in[5];
  const float* b2 = (const float*)d_in[6];
  const float* W3 = (const float*)d_in[7];
  const float* b3 = (const float*)d_in[8];
  const float* W4 = (const float*)d_in[9];
  const float* b4 = (const float*)d_in[10];
  const float* Wf = (const float*)d_in[11];
  const float* bf = (const float*)d_in[12];
  float* out      = (float*)d_out;
  _Float16* wsh   = (_Float16*)d_ws;    // needs 2*WELE*2 B = 1081344 B

  const int npts = in_sizes[0] / 3;

  conv_w<<<(WELE + 511) / 512, 512, 0, stream>>>(W1, W2, W4, W3, wsh);

  const int nblk = (npts + BN - 1) / BN;
  inr_fused<<<nblk, 512, 2 * BN * ROWB, stream>>>(x, W0, b0, b1, b2, b3, b4,
                                                  Wf, bf, wsh, out, npts);
}